// Round 12
// baseline (347.640 us; speedup 1.0000x reference)
//
#include <hip/hip_runtime.h>

#define NUM_E 1024
#define DIM 64
#define NROWS 65536                  // 64*32*32
#define OUT0_SIZE 4194304            // 64*64*32*32
#define OUT1_OFF OUT0_SIZE
#define LOSS_OFF (OUT0_SIZE + 65536) // 4259840
#define NSLICE 16                    // 1024 codes / 64 lanes
#define RPW 256                      // rows per wave

typedef __attribute__((ext_vector_type(16))) float sf16;

// ---------------- numpy pairwise sum(x*x), n=64 (validated bit-exact R3) ---
__device__ __forceinline__ float np_sumsq64_arr(const float* __restrict__ x) {
#pragma clang fp contract(off)
    float r[8];
#pragma unroll
    for (int j = 0; j < 8; ++j) r[j] = x[j] * x[j];
#pragma unroll
    for (int i = 8; i < 64; i += 8) {
#pragma unroll
        for (int j = 0; j < 8; ++j) {
            float p = x[i + j] * x[i + j];
            r[j] = r[j] + p;
        }
    }
    return ((r[0] + r[1]) + (r[2] + r[3])) + ((r[4] + r[5]) + (r[6] + r[7]));
}

// Prep: An[n] = np.sum(z_n*z_n), En[k] = np.sum(e_k*e_k); zero the loss slot.
__global__ __launch_bounds__(256) void vq_prep_kernel(const float* __restrict__ z,
                                                      const float* __restrict__ e,
                                                      float* __restrict__ En,
                                                      float* __restrict__ An,
                                                      float* __restrict__ out) {
    const int idx = blockIdx.x * 256 + threadIdx.x;   // grid covers 66560
    if (idx == 0) out[LOSS_OFF] = 0.0f;               // d_out re-poisoned every call
    const float* src;
    float* dst;
    if (idx < NROWS) { src = z + (size_t)idx * DIM; dst = An + idx; }
    else if (idx < NROWS + NUM_E) { src = e + (size_t)(idx - NROWS) * DIM; dst = En + (idx - NROWS); }
    else return;
    float xr[DIM];
    const float4* p = (const float4*)src;
#pragma unroll
    for (int i = 0; i < 16; ++i) {
        float4 v = p[i];
        xr[4*i+0] = v.x; xr[4*i+1] = v.y; xr[4*i+2] = v.z; xr[4*i+3] = v.w;
    }
    *dst = np_sumsq64_arr(xr);
}

// ---------------- scan: code-per-lane ----------------
// Wave = 64 codes (one per lane, e-row resident in 64 VGPRs, gathered once).
// Per row: z-row + A arrive via EXPLICIT s_load asm (wave-uniform -> SGPRs;
// the compiler refuses to scalarize uniform global loads itself: noclobber
// analysis. R4-R11: e went through broadcast VMEM + vector addressing, wall
// pinned at 172us regardless of z handling). Inner loop: 64 v_fma with SGPR
// z operand, sequential d=0..63 = bit-exact sgemm chain (validated R3).
#define EPIN8(a,b,c,d,f,g,h,i)                                                \
    do { asm volatile("" : "+v"(a), "+v"(b), "+v"(c), "+v"(d),                \
                           "+v"(f), "+v"(g), "+v"(h), "+v"(i)); } while (0)

__global__
__attribute__((amdgpu_flat_work_group_size(64, 64), amdgpu_waves_per_eu(4, 4)))
void vq_scan_kernel(const float* __restrict__ z,
                    const float* __restrict__ e,
                    const float* __restrict__ En,
                    const float* __restrict__ An,
                    float* __restrict__ sb,
                    int* __restrict__ kb) {
    const int lane  = threadIdx.x;                 // 64-thread (1-wave) blocks
    const int slice = blockIdx.x & (NSLICE - 1);
    const int row0  = (blockIdx.x >> 4) * RPW;
    const int kbase = slice * 64;
    const int klane = kbase + lane;

    // one-time per-lane gather of this lane's code row (64 VGPRs)
    float e0,e1,e2,e3,e4,e5,e6,e7,e8,e9,e10,e11,e12,e13,e14,e15,
          e16,e17,e18,e19,e20,e21,e22,e23,e24,e25,e26,e27,e28,e29,e30,e31,
          e32,e33,e34,e35,e36,e37,e38,e39,e40,e41,e42,e43,e44,e45,e46,e47,
          e48,e49,e50,e51,e52,e53,e54,e55,e56,e57,e58,e59,e60,e61,e62,e63;
    {
        const float4* ep = (const float4*)(e + (size_t)klane * DIM);
        float4 v;
        v=ep[0];  e0=v.x;  e1=v.y;  e2=v.z;  e3=v.w;
        v=ep[1];  e4=v.x;  e5=v.y;  e6=v.z;  e7=v.w;
        v=ep[2];  e8=v.x;  e9=v.y;  e10=v.z; e11=v.w;
        v=ep[3];  e12=v.x; e13=v.y; e14=v.z; e15=v.w;
        v=ep[4];  e16=v.x; e17=v.y; e18=v.z; e19=v.w;
        v=ep[5];  e20=v.x; e21=v.y; e22=v.z; e23=v.w;
        v=ep[6];  e24=v.x; e25=v.y; e26=v.z; e27=v.w;
        v=ep[7];  e28=v.x; e29=v.y; e30=v.z; e31=v.w;
        v=ep[8];  e32=v.x; e33=v.y; e34=v.z; e35=v.w;
        v=ep[9];  e36=v.x; e37=v.y; e38=v.z; e39=v.w;
        v=ep[10]; e40=v.x; e41=v.y; e42=v.z; e43=v.w;
        v=ep[11]; e44=v.x; e45=v.y; e46=v.z; e47=v.w;
        v=ep[12]; e48=v.x; e49=v.y; e50=v.z; e51=v.w;
        v=ep[13]; e52=v.x; e53=v.y; e54=v.z; e55=v.w;
        v=ep[14]; e56=v.x; e57=v.y; e58=v.z; e59=v.w;
        v=ep[15]; e60=v.x; e61=v.y; e62=v.z; e63=v.w;
    }
    const float enk = En[klane];                   // coalesced, 1 VGPR

#pragma unroll 1
    for (int r = 0; r < RPW; ++r) {
        const int row = row0 + r;
        // defensive: keep e non-rematerializable across the loop (free)
        EPIN8(e0,e1,e2,e3,e4,e5,e6,e7);       EPIN8(e8,e9,e10,e11,e12,e13,e14,e15);
        EPIN8(e16,e17,e18,e19,e20,e21,e22,e23); EPIN8(e24,e25,e26,e27,e28,e29,e30,e31);
        EPIN8(e32,e33,e34,e35,e36,e37,e38,e39); EPIN8(e40,e41,e42,e43,e44,e45,e46,e47);
        EPIN8(e48,e49,e50,e51,e52,e53,e54,e55); EPIN8(e56,e57,e58,e59,e60,e61,e62,e63);

        sf16 za, zc2, zc3, zc4; float As;
        {
            unsigned long long zaddr = (unsigned long long)(z + (size_t)row * DIM);
            unsigned long long aaddr = (unsigned long long)(An + row);
            asm volatile(
                "s_load_dwordx16 %0, %5, 0x0\n\t"
                "s_load_dwordx16 %1, %5, 0x40\n\t"
                "s_load_dwordx16 %2, %5, 0x80\n\t"
                "s_load_dwordx16 %3, %5, 0xc0\n\t"
                "s_load_dword    %4, %6, 0x0\n\t"
                "s_waitcnt lgkmcnt(0)"
                : "=s"(za), "=s"(zc2), "=s"(zc3), "=s"(zc4), "=s"(As)
                : "s"(zaddr), "s"(aaddr));
        }

        float m = 0.0f;   // sequential d = 0..63, one SGPR operand per FMA
        m=fmaf(e0, za[0], m);  m=fmaf(e1, za[1], m);  m=fmaf(e2, za[2], m);  m=fmaf(e3, za[3], m);
        m=fmaf(e4, za[4], m);  m=fmaf(e5, za[5], m);  m=fmaf(e6, za[6], m);  m=fmaf(e7, za[7], m);
        m=fmaf(e8, za[8], m);  m=fmaf(e9, za[9], m);  m=fmaf(e10,za[10],m);  m=fmaf(e11,za[11],m);
        m=fmaf(e12,za[12],m);  m=fmaf(e13,za[13],m);  m=fmaf(e14,za[14],m);  m=fmaf(e15,za[15],m);
        m=fmaf(e16,zc2[0], m); m=fmaf(e17,zc2[1], m); m=fmaf(e18,zc2[2], m); m=fmaf(e19,zc2[3], m);
        m=fmaf(e20,zc2[4], m); m=fmaf(e21,zc2[5], m); m=fmaf(e22,zc2[6], m); m=fmaf(e23,zc2[7], m);
        m=fmaf(e24,zc2[8], m); m=fmaf(e25,zc2[9], m); m=fmaf(e26,zc2[10],m); m=fmaf(e27,zc2[11],m);
        m=fmaf(e28,zc2[12],m); m=fmaf(e29,zc2[13],m); m=fmaf(e30,zc2[14],m); m=fmaf(e31,zc2[15],m);
        m=fmaf(e32,zc3[0], m); m=fmaf(e33,zc3[1], m); m=fmaf(e34,zc3[2], m); m=fmaf(e35,zc3[3], m);
        m=fmaf(e36,zc3[4], m); m=fmaf(e37,zc3[5], m); m=fmaf(e38,zc3[6], m); m=fmaf(e39,zc3[7], m);
        m=fmaf(e40,zc3[8], m); m=fmaf(e41,zc3[9], m); m=fmaf(e42,zc3[10],m); m=fmaf(e43,zc3[11],m);
        m=fmaf(e44,zc3[12],m); m=fmaf(e45,zc3[13],m); m=fmaf(e46,zc3[14],m); m=fmaf(e47,zc3[15],m);
        m=fmaf(e48,zc4[0], m); m=fmaf(e49,zc4[1], m); m=fmaf(e50,zc4[2], m); m=fmaf(e51,zc4[3], m);
        m=fmaf(e52,zc4[4], m); m=fmaf(e53,zc4[5], m); m=fmaf(e54,zc4[6], m); m=fmaf(e55,zc4[7], m);
        m=fmaf(e56,zc4[8], m); m=fmaf(e57,zc4[9], m); m=fmaf(e58,zc4[10],m); m=fmaf(e59,zc4[11],m);
        m=fmaf(e60,zc4[12],m); m=fmaf(e61,zc4[13],m); m=fmaf(e62,zc4[14],m); m=fmaf(e63,zc4[15],m);

        float s;
        {
#pragma clang fp contract(off)
            float twoM = 2.0f * m;                 // exact
            float t = As - twoM;                   // the ref's rounding grid
            s = t + enk;
        }

        // wave argmin: min-butterfly, then first lane holding the min
        float smin = s;
        smin = fminf(smin, __shfl_xor(smin, 1, 64));
        smin = fminf(smin, __shfl_xor(smin, 2, 64));
        smin = fminf(smin, __shfl_xor(smin, 4, 64));
        smin = fminf(smin, __shfl_xor(smin, 8, 64));
        smin = fminf(smin, __shfl_xor(smin, 16, 64));
        smin = fminf(smin, __shfl_xor(smin, 32, 64));
        unsigned long long bal = __ballot(s == smin);
        int ml = __ffsll((long long)bal) - 1;      // lowest lane = lowest k
        if (lane == ml) {
            sb[(size_t)row * NSLICE + slice] = s;
            kb[(size_t)row * NSLICE + slice] = klane;
        }
    }
}

// ---------------- finish: reduce 16 slices, gather, outputs + loss ----------
__global__ __launch_bounds__(256) void vq_finish_kernel(const float* __restrict__ z,
                                                        const float* __restrict__ e,
                                                        const float* __restrict__ sb,
                                                        const int* __restrict__ kb,
                                                        float* __restrict__ out) {
    const int n = blockIdx.x * 256 + threadIdx.x;

    float best = sb[(size_t)n * NSLICE];
    int bk = kb[(size_t)n * NSLICE];
#pragma unroll
    for (int q = 1; q < NSLICE; ++q) {
        float s = sb[(size_t)n * NSLICE + q];
        int k2 = kb[(size_t)n * NSLICE + q];
        if (s < best) { best = s; bk = k2; }       // ascending slice = ascending k
    }

    const int b  = n >> 10;       // H*W = 1024
    const int hw = n & 1023;
    const float* er = e + (size_t)bk * DIM;
    const float* zrp = z + (size_t)n * DIM;
    float* o0 = out + (size_t)b * 65536 + hw;      // out0[b, d, hw]
    float lsum = 0.0f;
#pragma unroll
    for (int d = 0; d < DIM; ++d) {
        float ev = er[d];                          // codebook L2-hot gather
        o0[(size_t)d * 1024] = ev;                 // coalesced across lanes per d
        float df = ev - zrp[d];
        lsum = fmaf(df, df, lsum);
    }
    out[OUT1_OFF + n] = (float)bk;

#pragma unroll
    for (int off = 32; off > 0; off >>= 1)
        lsum += __shfl_down(lsum, off, 64);
    __shared__ float wsum[4];
    const int lane = threadIdx.x & 63;
    const int wid  = threadIdx.x >> 6;
    if (lane == 0) wsum[wid] = lsum;
    __syncthreads();
    if (threadIdx.x == 0) {
        float bs = wsum[0] + wsum[1] + wsum[2] + wsum[3];
        // loss = (0.25 + 1.0) * mean(diff^2) over 4194304 elements
        atomicAdd(&out[LOSS_OFF], bs * (1.25f / 4194304.0f));
    }
}

extern "C" void kernel_launch(void* const* d_in, const int* in_sizes, int n_in,
                              void* d_out, int out_size, void* d_ws, size_t ws_size,
                              hipStream_t stream) {
    const float* z = (const float*)d_in[0];       // [65536, 64] fp32
    const float* e = (const float*)d_in[1];       // [1024, 64] fp32
    float* out = (float*)d_out;

    // ws: En (4 KB) | An (256 KB) | sb (4 MB) | kb (4 MB)
    float* En = (float*)d_ws;
    float* An = (float*)((char*)d_ws + 4096);
    float* sb = (float*)((char*)d_ws + 4096 + 262144);
    int*   kb = (int*)((char*)d_ws + 4096 + 262144 + (size_t)NROWS * NSLICE * 4);

    vq_prep_kernel<<<(NROWS + NUM_E + 255) / 256, 256, 0, stream>>>(z, e, En, An, out);
    vq_scan_kernel<<<(NROWS / RPW) * NSLICE, 64, 0, stream>>>(z, e, En, An, sb, kb);
    vq_finish_kernel<<<NROWS / 256, 256, 0, stream>>>(z, e, sb, kb, out);
}

// Round 14
// 236.284 us; speedup vs baseline: 1.4713x; 1.4713x over previous
//
#include <hip/hip_runtime.h>

#define NUM_E 1024
#define DIM 64
#define NROWS 65536                  // 64*32*32
#define OUT0_SIZE 4194304            // 64*64*32*32
#define OUT1_OFF OUT0_SIZE
#define LOSS_OFF (OUT0_SIZE + 65536) // 4259840
#define KSPLIT 4
#define KCHUNK (NUM_E / KSPLIT)      // 256 codes per slice

// ---------------- numpy pairwise sum(x*x), n=64 (validated bit-exact R3) ---
__device__ __forceinline__ float np_sumsq64_arr(const float* __restrict__ x) {
#pragma clang fp contract(off)
    float r[8];
#pragma unroll
    for (int j = 0; j < 8; ++j) r[j] = x[j] * x[j];
#pragma unroll
    for (int i = 8; i < 64; i += 8) {
#pragma unroll
        for (int j = 0; j < 8; ++j) {
            float p = x[i + j] * x[i + j];
            r[j] = r[j] + p;
        }
    }
    return ((r[0] + r[1]) + (r[2] + r[3])) + ((r[4] + r[5]) + (r[6] + r[7]));
}

// Prep: An[n] = np.sum(z_n*z_n), En[k] = np.sum(e_k*e_k); zero the loss slot.
__global__ __launch_bounds__(256) void vq_prep_kernel(const float* __restrict__ z,
                                                      const float* __restrict__ e,
                                                      float* __restrict__ En,
                                                      float* __restrict__ An,
                                                      float* __restrict__ out) {
    const int idx = blockIdx.x * 256 + threadIdx.x;   // grid covers 66560
    if (idx == 0) out[LOSS_OFF] = 0.0f;               // d_out re-poisoned every call
    const float* src;
    float* dst;
    if (idx < NROWS) { src = z + (size_t)idx * DIM; dst = An + idx; }
    else if (idx < NROWS + NUM_E) { src = e + (size_t)(idx - NROWS) * DIM; dst = En + (idx - NROWS); }
    else return;
    float xr[DIM];
    const float4* p = (const float4*)src;
#pragma unroll
    for (int i = 0; i < 16; ++i) {
        float4 v = p[i];
        xr[4*i+0] = v.x; xr[4*i+1] = v.y; xr[4*i+2] = v.z; xr[4*i+3] = v.w;
    }
    *dst = np_sumsq64_arr(xr);
}

// ---------------- scan: row-per-thread, whole k-loop in inline asm ----------
// R4-R12 lesson: the allocator ALWAYS sinks the long-lived per-lane array
// into the k-loop. Hard-coded registers in one asm blob:
//   v[40:103] = z row (loaded once, untouchable)
//   s[36:99]  = e row of code k via 4x s_load_dwordx16 (scalar pipe); s23=En[k]
//   v108      = running k (VGPR: v_cndmask vsrc1 must be VGPR - R13 error)
//   64x v_fmac_f32 v104, sN, vM : exact sequential sgemm chain (R3)
//   score: 2m = m+m; t = A-2m; s = En+t (commuted add, bit-identical)
//   strict < ascending k = np.argmin first-index ties.
// s32/s33 (SP/FP) are ABI-reserved -> e-rows start at s36.
__global__
__attribute__((amdgpu_flat_work_group_size(256, 256), amdgpu_waves_per_eu(4, 4)))
void vq_scan_kernel(const float* __restrict__ z,
                    const float* __restrict__ e,
                    const float* __restrict__ En,
                    const float* __restrict__ An,
                    float* __restrict__ sbest,
                    int* __restrict__ kbest) {
    const int bid = blockIdx.x;
    const int q = bid & (KSPLIT - 1);
    const int n = (bid >> 2) * 256 + threadIdx.x;

    const int k0 = q * KCHUNK;
    unsigned long long za = (unsigned long long)(z + (size_t)n * DIM);
    unsigned long long ea = (unsigned long long)(e + (size_t)k0 * DIM);
    unsigned long long na = (unsigned long long)(En + k0);
    const float Aval = An[n];

    float best;
    int bk;
    asm volatile(
        "s_mov_b64 s[16:17], %[ea]\n\t"
        "s_mov_b64 s[18:19], %[na]\n\t"
        "s_mov_b32 s20, 0\n\t"                 // iteration counter 0..KCHUNK
        "global_load_dwordx4 v[40:43],   %[za], off\n\t"
        "global_load_dwordx4 v[44:47],   %[za], off offset:16\n\t"
        "global_load_dwordx4 v[48:51],   %[za], off offset:32\n\t"
        "global_load_dwordx4 v[52:55],   %[za], off offset:48\n\t"
        "global_load_dwordx4 v[56:59],   %[za], off offset:64\n\t"
        "global_load_dwordx4 v[60:63],   %[za], off offset:80\n\t"
        "global_load_dwordx4 v[64:67],   %[za], off offset:96\n\t"
        "global_load_dwordx4 v[68:71],   %[za], off offset:112\n\t"
        "global_load_dwordx4 v[72:75],   %[za], off offset:128\n\t"
        "global_load_dwordx4 v[76:79],   %[za], off offset:144\n\t"
        "global_load_dwordx4 v[80:83],   %[za], off offset:160\n\t"
        "global_load_dwordx4 v[84:87],   %[za], off offset:176\n\t"
        "global_load_dwordx4 v[88:91],   %[za], off offset:192\n\t"
        "global_load_dwordx4 v[92:95],   %[za], off offset:208\n\t"
        "global_load_dwordx4 v[96:99],   %[za], off offset:224\n\t"
        "global_load_dwordx4 v[100:103], %[za], off offset:240\n\t"
        "v_mov_b32 v105, 0x7f7fffff\n\t"      // best = FLT_MAX
        "v_mov_b32 v106, 0\n\t"               // best k
        "v_mov_b32 v108, %[k0]\n\t"           // running k (VGPR)
        "s_waitcnt vmcnt(0)\n\t"
        "L_SCAN%=:\n\t"
        "s_load_dwordx16 s[36:51], s[16:17], 0x0\n\t"
        "s_load_dwordx16 s[52:67], s[16:17], 0x40\n\t"
        "s_load_dwordx16 s[68:83], s[16:17], 0x80\n\t"
        "s_load_dwordx16 s[84:99], s[16:17], 0xc0\n\t"
        "s_load_dword    s23,      s[18:19], 0x0\n\t"
        "v_mov_b32 v104, 0\n\t"
        "s_waitcnt lgkmcnt(0)\n\t"
        "v_fmac_f32 v104, s36, v40\n\t"  "v_fmac_f32 v104, s37, v41\n\t"
        "v_fmac_f32 v104, s38, v42\n\t"  "v_fmac_f32 v104, s39, v43\n\t"
        "v_fmac_f32 v104, s40, v44\n\t"  "v_fmac_f32 v104, s41, v45\n\t"
        "v_fmac_f32 v104, s42, v46\n\t"  "v_fmac_f32 v104, s43, v47\n\t"
        "v_fmac_f32 v104, s44, v48\n\t"  "v_fmac_f32 v104, s45, v49\n\t"
        "v_fmac_f32 v104, s46, v50\n\t"  "v_fmac_f32 v104, s47, v51\n\t"
        "v_fmac_f32 v104, s48, v52\n\t"  "v_fmac_f32 v104, s49, v53\n\t"
        "v_fmac_f32 v104, s50, v54\n\t"  "v_fmac_f32 v104, s51, v55\n\t"
        "v_fmac_f32 v104, s52, v56\n\t"  "v_fmac_f32 v104, s53, v57\n\t"
        "v_fmac_f32 v104, s54, v58\n\t"  "v_fmac_f32 v104, s55, v59\n\t"
        "v_fmac_f32 v104, s56, v60\n\t"  "v_fmac_f32 v104, s57, v61\n\t"
        "v_fmac_f32 v104, s58, v62\n\t"  "v_fmac_f32 v104, s59, v63\n\t"
        "v_fmac_f32 v104, s60, v64\n\t"  "v_fmac_f32 v104, s61, v65\n\t"
        "v_fmac_f32 v104, s62, v66\n\t"  "v_fmac_f32 v104, s63, v67\n\t"
        "v_fmac_f32 v104, s64, v68\n\t"  "v_fmac_f32 v104, s65, v69\n\t"
        "v_fmac_f32 v104, s66, v70\n\t"  "v_fmac_f32 v104, s67, v71\n\t"
        "v_fmac_f32 v104, s68, v72\n\t"  "v_fmac_f32 v104, s69, v73\n\t"
        "v_fmac_f32 v104, s70, v74\n\t"  "v_fmac_f32 v104, s71, v75\n\t"
        "v_fmac_f32 v104, s72, v76\n\t"  "v_fmac_f32 v104, s73, v77\n\t"
        "v_fmac_f32 v104, s74, v78\n\t"  "v_fmac_f32 v104, s75, v79\n\t"
        "v_fmac_f32 v104, s76, v80\n\t"  "v_fmac_f32 v104, s77, v81\n\t"
        "v_fmac_f32 v104, s78, v82\n\t"  "v_fmac_f32 v104, s79, v83\n\t"
        "v_fmac_f32 v104, s80, v84\n\t"  "v_fmac_f32 v104, s81, v85\n\t"
        "v_fmac_f32 v104, s82, v86\n\t"  "v_fmac_f32 v104, s83, v87\n\t"
        "v_fmac_f32 v104, s84, v88\n\t"  "v_fmac_f32 v104, s85, v89\n\t"
        "v_fmac_f32 v104, s86, v90\n\t"  "v_fmac_f32 v104, s87, v91\n\t"
        "v_fmac_f32 v104, s88, v92\n\t"  "v_fmac_f32 v104, s89, v93\n\t"
        "v_fmac_f32 v104, s90, v94\n\t"  "v_fmac_f32 v104, s91, v95\n\t"
        "v_fmac_f32 v104, s92, v96\n\t"  "v_fmac_f32 v104, s93, v97\n\t"
        "v_fmac_f32 v104, s94, v98\n\t"  "v_fmac_f32 v104, s95, v99\n\t"
        "v_fmac_f32 v104, s96, v100\n\t" "v_fmac_f32 v104, s97, v101\n\t"
        "v_fmac_f32 v104, s98, v102\n\t" "v_fmac_f32 v104, s99, v103\n\t"
        "v_add_f32 v107, v104, v104\n\t"      // 2m (exact)
        "v_sub_f32 v107, %[A], v107\n\t"      // t = A - 2m
        "v_add_f32 v107, s23, v107\n\t"       // s = En + t (== t + En bitwise)
        "v_cmp_lt_f32 vcc, v107, v105\n\t"    // strict < : first index wins
        "v_cndmask_b32 v105, v105, v107, vcc\n\t"
        "v_cndmask_b32 v106, v106, v108, vcc\n\t"
        "v_add_u32 v108, 1, v108\n\t"         // k++ (literal in src0: legal)
        "s_add_u32 s16, s16, 0x100\n\t"       // e row stride 256 B
        "s_addc_u32 s17, s17, 0\n\t"
        "s_add_u32 s18, s18, 4\n\t"
        "s_addc_u32 s19, s19, 0\n\t"
        "s_add_u32 s20, s20, 1\n\t"
        "s_cmp_lt_u32 s20, %[kc]\n\t"
        "s_cbranch_scc1 L_SCAN%=\n\t"
        "v_mov_b32 %[ob], v105\n\t"
        "v_mov_b32 %[ok], v106"
        : [ob] "=v"(best), [ok] "=v"(bk)
        : [ea] "s"(ea), [na] "s"(na), [k0] "s"(k0), [kc] "s"(KCHUNK),
          [za] "v"(za), [A] "v"(Aval)
        : "memory", "vcc", "scc",
          "s16","s17","s18","s19","s20","s23",
          "s36","s37","s38","s39","s40","s41","s42","s43",
          "s44","s45","s46","s47","s48","s49","s50","s51",
          "s52","s53","s54","s55","s56","s57","s58","s59",
          "s60","s61","s62","s63","s64","s65","s66","s67",
          "s68","s69","s70","s71","s72","s73","s74","s75",
          "s76","s77","s78","s79","s80","s81","s82","s83",
          "s84","s85","s86","s87","s88","s89","s90","s91",
          "s92","s93","s94","s95","s96","s97","s98","s99",
          "v40","v41","v42","v43","v44","v45","v46","v47",
          "v48","v49","v50","v51","v52","v53","v54","v55",
          "v56","v57","v58","v59","v60","v61","v62","v63",
          "v64","v65","v66","v67","v68","v69","v70","v71",
          "v72","v73","v74","v75","v76","v77","v78","v79",
          "v80","v81","v82","v83","v84","v85","v86","v87",
          "v88","v89","v90","v91","v92","v93","v94","v95",
          "v96","v97","v98","v99","v100","v101","v102","v103",
          "v104","v105","v106","v107","v108");

    sbest[(size_t)n * KSPLIT + q] = best;
    kbest[(size_t)n * KSPLIT + q] = bk;
}

// ---------------- finish: reduce 4 slices, gather, outputs + loss (R4) -----
__global__ __launch_bounds__(256) void vq_finish_kernel(const float* __restrict__ z,
                                                        const float* __restrict__ e,
                                                        const float* __restrict__ sbest,
                                                        const int* __restrict__ kbest,
                                                        float* __restrict__ out) {
    const int n = blockIdx.x * 256 + threadIdx.x;

    float best = sbest[(size_t)n * KSPLIT];
    int bk = kbest[(size_t)n * KSPLIT];
#pragma unroll
    for (int q = 1; q < KSPLIT; ++q) {
        float s = sbest[(size_t)n * KSPLIT + q];
        int k2 = kbest[(size_t)n * KSPLIT + q];
        if (s < best) { best = s; bk = k2; }         // ties keep lower q (= lower k)
    }

    const int b  = n >> 10;       // H*W = 1024
    const int hw = n & 1023;
    const float* er = e + (size_t)bk * DIM;
    const float* zrp = z + (size_t)n * DIM;
    float* o0 = out + (size_t)b * 65536 + hw;        // out0[b, d, hw]
    float lsum = 0.0f;
#pragma unroll
    for (int d = 0; d < DIM; ++d) {
        float ev = er[d];                            // codebook L2-hot gather
        o0[(size_t)d * 1024] = ev;                   // coalesced across lanes per d
        float df = ev - zrp[d];
        lsum = fmaf(df, df, lsum);
    }
    out[OUT1_OFF + n] = (float)bk;

#pragma unroll
    for (int off = 32; off > 0; off >>= 1)
        lsum += __shfl_down(lsum, off, 64);
    __shared__ float wsum[4];
    const int lane = threadIdx.x & 63;
    const int wid  = threadIdx.x >> 6;
    if (lane == 0) wsum[wid] = lsum;
    __syncthreads();
    if (threadIdx.x == 0) {
        float bs = wsum[0] + wsum[1] + wsum[2] + wsum[3];
        // loss = (0.25 + 1.0) * mean(diff^2) over 4194304 elements
        atomicAdd(&out[LOSS_OFF], bs * (1.25f / 4194304.0f));
    }
}

extern "C" void kernel_launch(void* const* d_in, const int* in_sizes, int n_in,
                              void* d_out, int out_size, void* d_ws, size_t ws_size,
                              hipStream_t stream) {
    const float* z = (const float*)d_in[0];       // [65536, 64] fp32
    const float* e = (const float*)d_in[1];       // [1024, 64] fp32
    float* out = (float*)d_out;

    // ws: En (4 KB) | An (256 KB) | sbest (1 MB) | kbest (1 MB)
    float* En = (float*)d_ws;
    float* An = (float*)((char*)d_ws + 4096);
    float* sb = (float*)((char*)d_ws + 4096 + 262144);
    int*   kb = (int*)((char*)d_ws + 4096 + 262144 + (size_t)NROWS * KSPLIT * 4);

    vq_prep_kernel<<<(NROWS + NUM_E + 255) / 256, 256, 0, stream>>>(z, e, En, An, out);
    vq_scan_kernel<<<(NROWS / 256) * KSPLIT, 256, 0, stream>>>(z, e, En, An, sb, kb);
    vq_finish_kernel<<<NROWS / 256, 256, 0, stream>>>(z, e, sb, kb, out);
}